// Round 7
// baseline (279.549 us; speedup 1.0000x reference)
//
#include <hip/hip_runtime.h>
#include <hip/hip_bf16.h>

#define N_ATOMS 131072
#define DQ 256
#define H1 512
#define NTYPES 4
#define TILE_M 64
#define GRID 1024   // waterfall: ~2 tiles/block; 512 co-resident (LDS-limited)

typedef __bf16 bf16x8 __attribute__((ext_vector_type(8)));
typedef float f32x16 __attribute__((ext_vector_type(16)));

__device__ __forceinline__ unsigned short f2bf(float f) {
  unsigned int u = __builtin_bit_cast(unsigned int, f);
  u += 0x7fffu + ((u >> 16) & 1u);   // round-to-nearest-even (inputs finite)
  return (unsigned short)(u >> 16);
}

__device__ __forceinline__ float fast_tanh(float x) {
  float e = __expf(2.0f * x);
  return 1.0f - 2.0f * __builtin_amdgcn_rcpf(e + 1.0f);
}

// ---------------------------------------------------------------------------
// init: zero cnt[4] + ticket device-side (graph-capture safe)
// ---------------------------------------------------------------------------
__global__ __launch_bounds__(64) void init_kernel(int* __restrict__ hdr) {
  if (threadIdx.x < 16) hdr[threadIdx.x] = 0;
}

// ---------------------------------------------------------------------------
// prep (fused): (a) W0 fp32 -> bf16 pre-swizzled [t][k/8][n][8k],
// (b) block-aggregated scatter of atom ids into FIXED per-type perm regions
// (perm[t*N + j], j < cnt[t]).
// ---------------------------------------------------------------------------
__global__ __launch_bounds__(256) void prep_kernel(
    const float* __restrict__ W0, const int* __restrict__ Z,
    unsigned short* __restrict__ W0s, int* __restrict__ perm,
    int* __restrict__ cnt)
{
  const int b = blockIdx.x, tid = threadIdx.x;
  const int gid = b * 256 + tid;

  if (gid < NTYPES * (DQ / 8) * H1) {   // 65536 16-byte chunks
    const int n  = gid & (H1 - 1);
    const int kg = (gid >> 9) & 31;
    const int t  = gid >> 14;
    const float* src = W0 + ((size_t)(t * DQ + kg * 8) * H1 + n);
    unsigned short o[8];
#pragma unroll
    for (int j = 0; j < 8; ++j) o[j] = f2bf(src[(size_t)j * H1]);
    uint4 v;
    v.x = (unsigned)o[0] | ((unsigned)o[1] << 16);
    v.y = (unsigned)o[2] | ((unsigned)o[3] << 16);
    v.z = (unsigned)o[4] | ((unsigned)o[5] << 16);
    v.w = (unsigned)o[6] | ((unsigned)o[7] << 16);
    ((uint4*)W0s)[gid] = v;
  }

  __shared__ int lc[NTYPES], lbase[NTYPES];
  if (tid < NTYPES) lc[tid] = 0;
  __syncthreads();
  const int t  = Z[gid];                 // grid 512*256 == N exactly
  const int my = atomicAdd(&lc[t], 1);
  __syncthreads();
  if (tid < NTYPES) lbase[tid] = lc[tid] ? atomicAdd(&cnt[tid], lc[tid]) : 0;
  __syncthreads();
  perm[t * N_ATOMS + lbase[t] + my] = gid;
}

// ---------------------------------------------------------------------------
// half-tile staging: 8 float4 (32 VGPRs) per phase, consumed before the next
// phase is issued -> never 64 staging VGPRs live alongside the 128-AGPR
// accumulator (v5's scratch-spill mode, WRITE_SIZE 109 MB).
// ---------------------------------------------------------------------------
__device__ __forceinline__ void issue_half(float4* st, const float* q,
                                           int atom, int c4, int h) {
  const float* p = q + (size_t)atom * DQ + c4 * 64 + h * 32;
#pragma unroll
  for (int i = 0; i < 8; ++i) st[i] = *(const float4*)(p + i * 4);
}

__device__ __forceinline__ void store_half(
    const float4* st, unsigned short (*A)[TILE_M][8], int row, int c4, int h) {
#pragma unroll
  for (int i2 = 0; i2 < 4; ++i2) {
    const int k = c4 * 64 + h * 32 + i2 * 8;   // k & 7 == 0 -> 16B-aligned
    uint4 vv;
    vv.x = (unsigned)f2bf(st[2*i2].x)   | ((unsigned)f2bf(st[2*i2].y)   << 16);
    vv.y = (unsigned)f2bf(st[2*i2].z)   | ((unsigned)f2bf(st[2*i2].w)   << 16);
    vv.z = (unsigned)f2bf(st[2*i2+1].x) | ((unsigned)f2bf(st[2*i2+1].y) << 16);
    vv.w = (unsigned)f2bf(st[2*i2+1].z) | ((unsigned)f2bf(st[2*i2+1].w) << 16);
    *(uint4*)&A[k >> 3][row][0] = vv;
  }
}

// ---------------------------------------------------------------------------
// gemm_persist: GRID blocks waterfalling over the compact tile space via a
// dynamic ticket (quantum = block lifetime ~2 tiles -> no 5-tile straggler:
// round 6 measured dur = 5*T while the majority finished at 4*T). Per tile:
// K-loop (LDS A, L2 B, setprio) -> b0/W1 loads -> half-gather #1 ->
// epilogue mt=0 (covers #1) -> store #1 -> half-gather #2 -> epilogue mt=1
// -> store #2 -> one barrier.
// ---------------------------------------------------------------------------
__global__ __launch_bounds__(256, 2) void gemm_persist(
    const float* __restrict__ q, const int* __restrict__ perm,
    const int* __restrict__ cnt, int* __restrict__ ticket,
    const unsigned short* __restrict__ W0s,
    const float* __restrict__ b0g, const float* __restrict__ W1,
    const float* __restrict__ b1p, float* __restrict__ out)
{
  __shared__ unsigned short Alds[2][DQ / 8][TILE_M][8];  // 64 KB
  __shared__ float Fws[2][4][TILE_M];                    // 2 KB
  __shared__ int shvt[2];                                // ticket broadcast

  const int tid = threadIdx.x;
  const int l = tid & 63, w = tid >> 6;
  const int half = l >> 5, ln = l & 31;
  const int row = tid >> 2, c4 = tid & 3;

  const int c0 = cnt[0], c1 = cnt[1], c2 = cnt[2], c3 = cnt[3];
  const int n0 = (c0 + 63) >> 6, n1 = (c1 + 63) >> 6;
  const int n2 = (c2 + 63) >> 6, n3 = (c3 + 63) >> 6;
  const int p1 = n0, p2 = n0 + n1, p3 = n0 + n1 + n2;
  const int total = n0 + n1 + n2 + n3;   // 2048..2051 (>= 2048 > GRID/2)
  const float b1v = b1p[0];

#define DECODE(v, T, J0, CT) do {                                   \
    T = ((v) >= p1) + ((v) >= p2) + ((v) >= p3);                    \
    const int pre_ = (T == 0) ? 0 : (T == 1) ? p1 : (T == 2) ? p2 : p3; \
    CT = (T == 0) ? c0 : (T == 1) ? c1 : (T == 2) ? c2 : c3;        \
    J0 = ((v) - pre_) * TILE_M; } while (0)

  // epilogue half MT: consumes acc[MT][*], writes Fws rows MT*32..MT*32+31
#define EPI_HALF(MT) do {                                                     \
    _Pragma("unroll")                                                         \
    for (int r = 0; r < 16; ++r) {                                            \
      float s = 0.f;                                                          \
      _Pragma("unroll")                                                       \
      for (int nt = 0; nt < 4; ++nt)                                          \
        s += w1v[nt] * fast_tanh(acc[MT][nt][r] + b0v[nt]);                   \
      s += __shfl_xor(s, 1);                                                  \
      s += __shfl_xor(s, 2);                                                  \
      s += __shfl_xor(s, 4);                                                  \
      s += __shfl_xor(s, 8);                                                  \
      s += __shfl_xor(s, 16);                                                 \
      if (ln == 0)                                                            \
        Fws[cur][w][(MT) * 32 + (r & 3) + 8 * (r >> 2) + 4 * half] = s;       \
    }                                                                         \
  } while (0)

  // ---- prologue: static tile blockIdx.x into buf 0 (total >= GRID*2... ----
  // total >= 2048 >= GRID, so every block's static tile is valid)
  int vt_cur = (int)blockIdx.x;
  int t_cur, j0_cur, ct_cur;
  DECODE(vt_cur, t_cur, j0_cur, ct_cur);

  float4 st[8];
  {
    int atom = 0;
    if (j0_cur + row < ct_cur) atom = perm[t_cur * N_ATOMS + j0_cur + row];
    issue_half(st, q, atom, c4, 0);
    store_half(st, Alds[0], row, c4, 0);
    issue_half(st, q, atom, c4, 1);
    store_half(st, Alds[0], row, c4, 1);
  }
  if (tid == 0) shvt[0] = GRID + atomicAdd(ticket, 1);
  __syncthreads();

  int vt_nxt = shvt[0];
  int t_nxt = 0, j0_nxt = 0, ct_nxt = 0, anext = 0;
  if (vt_nxt < total) {
    DECODE(vt_nxt, t_nxt, j0_nxt, ct_nxt);
    if (j0_nxt + row < ct_nxt) anext = perm[t_nxt * N_ATOMS + j0_nxt + row];
  }
  int cur = 0, par = 0;

  while (vt_cur < total) {
    // ---- a. K-loop on Alds[cur], B from L2 (pre-swizzled W0s) ----
    f32x16 acc[2][4];
#pragma unroll
    for (int mt = 0; mt < 2; ++mt)
#pragma unroll
      for (int nt = 0; nt < 4; ++nt) acc[mt][nt] = (f32x16)0.0f;

    const unsigned short* Bt = W0s + (size_t)t_cur * (DQ * H1);
    const unsigned short* Bbase = Bt + (size_t)(w * 128 + ln) * 8;

    __builtin_amdgcn_s_setprio(1);
#pragma unroll 4
    for (int step = 0; step < 16; ++step) {
      const int kg = 2 * step + half;
      const bf16x8 a0 = *(const bf16x8*)&Alds[cur][kg][ln][0];
      const bf16x8 a1 = *(const bf16x8*)&Alds[cur][kg][32 + ln][0];
      const unsigned short* bp = Bbase + (size_t)kg * (H1 * 8);
      const bf16x8 b0f = *(const bf16x8*)(bp);
      const bf16x8 b1f = *(const bf16x8*)(bp + 32 * 8);
      const bf16x8 b2f = *(const bf16x8*)(bp + 64 * 8);
      const bf16x8 b3f = *(const bf16x8*)(bp + 96 * 8);
      acc[0][0] = __builtin_amdgcn_mfma_f32_32x32x16_bf16(a0, b0f, acc[0][0], 0, 0, 0);
      acc[1][0] = __builtin_amdgcn_mfma_f32_32x32x16_bf16(a1, b0f, acc[1][0], 0, 0, 0);
      acc[0][1] = __builtin_amdgcn_mfma_f32_32x32x16_bf16(a0, b1f, acc[0][1], 0, 0, 0);
      acc[1][1] = __builtin_amdgcn_mfma_f32_32x32x16_bf16(a1, b1f, acc[1][1], 0, 0, 0);
      acc[0][2] = __builtin_amdgcn_mfma_f32_32x32x16_bf16(a0, b2f, acc[0][2], 0, 0, 0);
      acc[1][2] = __builtin_amdgcn_mfma_f32_32x32x16_bf16(a1, b2f, acc[1][2], 0, 0, 0);
      acc[0][3] = __builtin_amdgcn_mfma_f32_32x32x16_bf16(a0, b3f, acc[0][3], 0, 0, 0);
      acc[1][3] = __builtin_amdgcn_mfma_f32_32x32x16_bf16(a1, b3f, acc[1][3], 0, 0, 0);
    }
    __builtin_amdgcn_s_setprio(0);

    const bool have_nxt = (vt_nxt < total);

    // ---- b. per-column b0/W1 FIRST (older in vmcnt FIFO than the gather:
    // the epilogue's wait on them is counted, not a drain) ----
    float b0v[4], w1v[4];
#pragma unroll
    for (int nt = 0; nt < 4; ++nt) {
      const int c = w * 128 + nt * 32 + ln;
      b0v[nt] = b0g[t_cur * H1 + c];
      w1v[nt] = W1[t_cur * H1 + c];
    }

    // ---- c. half-gather #1 -> epilogue mt=0 covers it -> store #1 ----
    if (have_nxt) issue_half(st, q, anext, c4, 0);
    EPI_HALF(0);
    if (have_nxt) store_half(st, Alds[cur ^ 1], row, c4, 0);

    // ---- d. half-gather #2 (reuses st regs) -> epilogue mt=1 -> store #2 --
    if (have_nxt) issue_half(st, q, anext, c4, 1);
    EPI_HALF(1);
    if (have_nxt) store_half(st, Alds[cur ^ 1], row, c4, 1);

    // ---- e. ticket for tile n+2 (double-buffered broadcast slot) ----
    if (tid == 0 && have_nxt) shvt[par ^ 1] = GRID + atomicAdd(ticket, 1);

    __syncthreads();   // Fws[cur] + Alds[cur^1] + shvt[par^1] all ready

    // ---- f. out-write from Fws[cur] ----
    if (tid < TILE_M && j0_cur + tid < ct_cur) {
      const int a = perm[t_cur * N_ATOMS + j0_cur + tid];
      out[a] = Fws[cur][0][tid] + Fws[cur][1][tid] + Fws[cur][2][tid]
             + Fws[cur][3][tid] + b1v;
    }

    // ---- g. advance ----
    if (have_nxt) {
      vt_cur = vt_nxt; t_cur = t_nxt; j0_cur = j0_nxt; ct_cur = ct_nxt;
      vt_nxt = shvt[par ^ 1];
      anext = 0;
      if (vt_nxt < total) {
        DECODE(vt_nxt, t_nxt, j0_nxt, ct_nxt);
        if (j0_nxt + row < ct_nxt) anext = perm[t_nxt * N_ATOMS + j0_nxt + row];
      }
    } else {
      vt_cur = total;
    }
    cur ^= 1; par ^= 1;
  }
#undef DECODE
#undef EPI_HALF
}

extern "C" void kernel_launch(void* const* d_in, const int* in_sizes, int n_in,
                              void* d_out, int out_size, void* d_ws, size_t ws_size,
                              hipStream_t stream) {
  const float* q  = (const float*)d_in[0];
  const int*   Z  = (const int*)d_in[1];
  const float* W0 = (const float*)d_in[2];
  const float* b0 = (const float*)d_in[3];
  const float* W1 = (const float*)d_in[4];
  const float* b1 = (const float*)d_in[5];
  float* out = (float*)d_out;

  char* ws = (char*)d_ws;
  int* hdr    = (int*)(ws);                        // cnt[4] + ticket + pad
  int* cnt    = hdr;
  int* ticket = hdr + 4;
  int* perm   = (int*)(ws + 64);                   // 4*N ints = 2 MB
  unsigned short* W0s =
      (unsigned short*)(ws + 64 + (size_t)NTYPES * N_ATOMS * 4);  // 1 MB

  hipLaunchKernelGGL(init_kernel, dim3(1), dim3(64), 0, stream, hdr);
  hipLaunchKernelGGL(prep_kernel, dim3(512), dim3(256), 0, stream,
                     W0, Z, W0s, perm, cnt);
  hipLaunchKernelGGL(gemm_persist, dim3(GRID), dim3(256), 0, stream,
                     q, perm, cnt, ticket, W0s, b0, W1, b1, out);
}

// Round 9
// 271.796 us; speedup vs baseline: 1.0285x; 1.0285x over previous
//
#include <hip/hip_runtime.h>
#include <hip/hip_bf16.h>

#define N_ATOMS 131072
#define DQ 256
#define H1 512
#define NTYPES 4
#define TILE_M 64
#define GRID 512    // persistent, 2/CU; static stride-512 tile schedule

typedef __bf16 bf16x8 __attribute__((ext_vector_type(8)));
typedef float f32x16 __attribute__((ext_vector_type(16)));

__device__ __forceinline__ unsigned short f2bf(float f) {
  unsigned int u = __builtin_bit_cast(unsigned int, f);
  u += 0x7fffu + ((u >> 16) & 1u);   // round-to-nearest-even (inputs finite)
  return (unsigned short)(u >> 16);
}

__device__ __forceinline__ float fast_tanh(float x) {
  float e = __expf(2.0f * x);
  return 1.0f - 2.0f * __builtin_amdgcn_rcpf(e + 1.0f);
}

// ---------------------------------------------------------------------------
// init: zero cnt[4] device-side (graph-capture safe)
// ---------------------------------------------------------------------------
__global__ __launch_bounds__(64) void init_kernel(int* __restrict__ hdr) {
  if (threadIdx.x < 16) hdr[threadIdx.x] = 0;
}

// ---------------------------------------------------------------------------
// prep (fused): (a) W0 fp32 -> bf16 pre-swizzled [t][k/8][n][8k],
// (b) block-aggregated scatter of atom ids into FIXED per-type perm regions
// (perm[t*N + j], j < cnt[t]).
// ---------------------------------------------------------------------------
__global__ __launch_bounds__(256) void prep_kernel(
    const float* __restrict__ W0, const int* __restrict__ Z,
    unsigned short* __restrict__ W0s, int* __restrict__ perm,
    int* __restrict__ cnt)
{
  const int b = blockIdx.x, tid = threadIdx.x;
  const int gid = b * 256 + tid;

  if (gid < NTYPES * (DQ / 8) * H1) {   // 65536 16-byte chunks
    const int n  = gid & (H1 - 1);
    const int kg = (gid >> 9) & 31;
    const int t  = gid >> 14;
    const float* src = W0 + ((size_t)(t * DQ + kg * 8) * H1 + n);
    unsigned short o[8];
#pragma unroll
    for (int j = 0; j < 8; ++j) o[j] = f2bf(src[(size_t)j * H1]);
    uint4 v;
    v.x = (unsigned)o[0] | ((unsigned)o[1] << 16);
    v.y = (unsigned)o[2] | ((unsigned)o[3] << 16);
    v.z = (unsigned)o[4] | ((unsigned)o[5] << 16);
    v.w = (unsigned)o[6] | ((unsigned)o[7] << 16);
    ((uint4*)W0s)[gid] = v;
  }

  __shared__ int lc[NTYPES], lbase[NTYPES];
  if (tid < NTYPES) lc[tid] = 0;
  __syncthreads();
  const int t  = Z[gid];                 // grid 512*256 == N exactly
  const int my = atomicAdd(&lc[t], 1);
  __syncthreads();
  if (tid < NTYPES) lbase[tid] = lc[tid] ? atomicAdd(&cnt[tid], lc[tid]) : 0;
  __syncthreads();
  perm[t * N_ATOMS + lbase[t] + my] = gid;
}

// ---------------------------------------------------------------------------
// half-tile staging: 8 float4 (32 VGPRs) per phase, consumed before the next
// phase is issued -> never 64 staging VGPRs live alongside the 128-AGPR
// accumulator (the v5 scratch-spill mode, WRITE_SIZE 109 MB).
// ---------------------------------------------------------------------------
__device__ __forceinline__ void issue_half(float4* st, const float* q,
                                           int atom, int c4, int h) {
  const float* p = q + (size_t)atom * DQ + c4 * 64 + h * 32;
#pragma unroll
  for (int i = 0; i < 8; ++i) st[i] = *(const float4*)(p + i * 4);
}

__device__ __forceinline__ void store_half(
    const float4* st, unsigned short (*A)[TILE_M][8], int row, int c4, int h) {
#pragma unroll
  for (int i2 = 0; i2 < 4; ++i2) {
    const int k = c4 * 64 + h * 32 + i2 * 8;   // k & 7 == 0 -> 16B-aligned
    uint4 vv;
    vv.x = (unsigned)f2bf(st[2*i2].x)   | ((unsigned)f2bf(st[2*i2].y)   << 16);
    vv.y = (unsigned)f2bf(st[2*i2].z)   | ((unsigned)f2bf(st[2*i2].w)   << 16);
    vv.z = (unsigned)f2bf(st[2*i2+1].x) | ((unsigned)f2bf(st[2*i2+1].y) << 16);
    vv.w = (unsigned)f2bf(st[2*i2+1].z) | ((unsigned)f2bf(st[2*i2+1].w) << 16);
    *(uint4*)&A[k >> 3][row][0] = vv;
  }
}

// ---------------------------------------------------------------------------
// gemm_persist: 512 persistent blocks, STATIC stride-512 tile schedule (no
// ticket: round-7 showed dynamic scheduling adds only overhead). Per tile:
// K-loop (LDS A, L2 B, setprio) -> b0/W1 -> half-gather #1 -> epilogue mt=0
// -> store #1 -> half-gather #2 -> epilogue mt=1 -> store #2 -> one barrier.
//
// K-PHASE ROTATION: block bx starts the K-loop at step (bx&15). All ~2048
// concurrent waves otherwise read the SAME W0s lines in the SAME order from
// the same phase -> same-line L2 contention (~1600 cyc stall per 4-step
// window inferred from rounds 6/7). Rotating the start phase spreads reads
// across the whole 1 MB W0s working set. Accumulation order within K is
// permuted only (fp delta << tolerance).
// ---------------------------------------------------------------------------
__global__ __launch_bounds__(256, 2) void gemm_persist(
    const float* __restrict__ q, const int* __restrict__ perm,
    const int* __restrict__ cnt,
    const unsigned short* __restrict__ W0s,
    const float* __restrict__ b0g, const float* __restrict__ W1,
    const float* __restrict__ b1p, float* __restrict__ out)
{
  __shared__ unsigned short Alds[2][DQ / 8][TILE_M][8];  // 64 KB
  __shared__ float Fws[2][4][TILE_M];                    // 2 KB

  const int tid = threadIdx.x;
  const int l = tid & 63, w = tid >> 6;
  const int half = l >> 5, ln = l & 31;
  const int row = tid >> 2, c4 = tid & 3;
  const int bx = (int)blockIdx.x;
  const int kphase = bx & 15;            // per-block K-phase offset

  const int c0 = cnt[0], c1 = cnt[1], c2 = cnt[2], c3 = cnt[3];
  const int n0 = (c0 + 63) >> 6, n1 = (c1 + 63) >> 6;
  const int n2 = (c2 + 63) >> 6, n3 = (c3 + 63) >> 6;
  const int p1 = n0, p2 = n0 + n1, p3 = n0 + n1 + n2;
  const int total = n0 + n1 + n2 + n3;   // 2048..2051 (>= GRID)
  const float b1v = b1p[0];

#define DECODE(v, T, J0, CT) do {                                   \
    T = ((v) >= p1) + ((v) >= p2) + ((v) >= p3);                    \
    const int pre_ = (T == 0) ? 0 : (T == 1) ? p1 : (T == 2) ? p2 : p3; \
    CT = (T == 0) ? c0 : (T == 1) ? c1 : (T == 2) ? c2 : c3;        \
    J0 = ((v) - pre_) * TILE_M; } while (0)

  // epilogue half MT: consumes acc[MT][*], writes Fws rows MT*32..MT*32+31
#define EPI_HALF(MT) do {                                                     \
    _Pragma("unroll")                                                         \
    for (int r = 0; r < 16; ++r) {                                            \
      float s = 0.f;                                                          \
      _Pragma("unroll")                                                       \
      for (int nt = 0; nt < 4; ++nt)                                          \
        s += w1v[nt] * fast_tanh(acc[MT][nt][r] + b0v[nt]);                   \
      s += __shfl_xor(s, 1);                                                  \
      s += __shfl_xor(s, 2);                                                  \
      s += __shfl_xor(s, 4);                                                  \
      s += __shfl_xor(s, 8);                                                  \
      s += __shfl_xor(s, 16);                                                 \
      if (ln == 0)                                                            \
        Fws[cur][w][(MT) * 32 + (r & 3) + 8 * (r >> 2) + 4 * half] = s;       \
    }                                                                         \
  } while (0)

  // ---- prologue: tile bx into buf 0 (total >= 2048 > GRID, always valid) --
  int vt_cur = bx;
  int t_cur, j0_cur, ct_cur;
  DECODE(vt_cur, t_cur, j0_cur, ct_cur);

  float4 st[8];
  {
    int atom = 0;
    if (j0_cur + row < ct_cur) atom = perm[t_cur * N_ATOMS + j0_cur + row];
    issue_half(st, q, atom, c4, 0);
    store_half(st, Alds[0], row, c4, 0);
    issue_half(st, q, atom, c4, 1);
    store_half(st, Alds[0], row, c4, 1);
  }
  __syncthreads();

  int vt_nxt = bx + GRID;
  int t_nxt = 0, j0_nxt = 0, ct_nxt = 0, anext = 0;
  if (vt_nxt < total) {
    DECODE(vt_nxt, t_nxt, j0_nxt, ct_nxt);
    if (j0_nxt + row < ct_nxt) anext = perm[t_nxt * N_ATOMS + j0_nxt + row];
  }
  int cur = 0;

  while (vt_cur < total) {
    // ---- a. K-loop on Alds[cur], B from L2, phase-rotated by kphase ----
    f32x16 acc[2][4];
#pragma unroll
    for (int mt = 0; mt < 2; ++mt)
#pragma unroll
      for (int nt = 0; nt < 4; ++nt) acc[mt][nt] = (f32x16)0.0f;

    const unsigned short* Bt = W0s + (size_t)t_cur * (DQ * H1);
    const unsigned short* Bbase = Bt + (size_t)(w * 128 + ln) * 8;

    __builtin_amdgcn_s_setprio(1);
#pragma unroll 4
    for (int step = 0; step < 16; ++step) {
      const int kg = 2 * ((step + kphase) & 15) + half;
      const bf16x8 a0 = *(const bf16x8*)&Alds[cur][kg][ln][0];
      const bf16x8 a1 = *(const bf16x8*)&Alds[cur][kg][32 + ln][0];
      const unsigned short* bptr = Bbase + (size_t)kg * (H1 * 8);
      const bf16x8 b0f = *(const bf16x8*)(bptr);
      const bf16x8 b1f = *(const bf16x8*)(bptr + 32 * 8);
      const bf16x8 b2f = *(const bf16x8*)(bptr + 64 * 8);
      const bf16x8 b3f = *(const bf16x8*)(bptr + 96 * 8);
      acc[0][0] = __builtin_amdgcn_mfma_f32_32x32x16_bf16(a0, b0f, acc[0][0], 0, 0, 0);
      acc[1][0] = __builtin_amdgcn_mfma_f32_32x32x16_bf16(a1, b0f, acc[1][0], 0, 0, 0);
      acc[0][1] = __builtin_amdgcn_mfma_f32_32x32x16_bf16(a0, b1f, acc[0][1], 0, 0, 0);
      acc[1][1] = __builtin_amdgcn_mfma_f32_32x32x16_bf16(a1, b1f, acc[1][1], 0, 0, 0);
      acc[0][2] = __builtin_amdgcn_mfma_f32_32x32x16_bf16(a0, b2f, acc[0][2], 0, 0, 0);
      acc[1][2] = __builtin_amdgcn_mfma_f32_32x32x16_bf16(a1, b2f, acc[1][2], 0, 0, 0);
      acc[0][3] = __builtin_amdgcn_mfma_f32_32x32x16_bf16(a0, b3f, acc[0][3], 0, 0, 0);
      acc[1][3] = __builtin_amdgcn_mfma_f32_32x32x16_bf16(a1, b3f, acc[1][3], 0, 0, 0);
    }
    __builtin_amdgcn_s_setprio(0);

    const bool have_nxt = (vt_nxt < total);

    // ---- b. per-column b0/W1 FIRST (older in vmcnt FIFO than the gather:
    // the epilogue's wait on them is counted, not a drain) ----
    float b0v[4], w1v[4];
#pragma unroll
    for (int nt = 0; nt < 4; ++nt) {
      const int c = w * 128 + nt * 32 + ln;
      b0v[nt] = b0g[t_cur * H1 + c];
      w1v[nt] = W1[t_cur * H1 + c];
    }

    // ---- c. half-gather #1 -> epilogue mt=0 covers it -> store #1 ----
    if (have_nxt) issue_half(st, q, anext, c4, 0);
    EPI_HALF(0);
    if (have_nxt) store_half(st, Alds[cur ^ 1], row, c4, 0);

    // ---- d. half-gather #2 (reuses st regs) -> epilogue mt=1 -> store #2 --
    if (have_nxt) issue_half(st, q, anext, c4, 1);
    EPI_HALF(1);
    if (have_nxt) store_half(st, Alds[cur ^ 1], row, c4, 1);

    __syncthreads();   // Fws[cur] + Alds[cur^1] ready

    // ---- e. out-write from Fws[cur] ----
    if (tid < TILE_M && j0_cur + tid < ct_cur) {
      const int a = perm[t_cur * N_ATOMS + j0_cur + tid];
      out[a] = Fws[cur][0][tid] + Fws[cur][1][tid] + Fws[cur][2][tid]
             + Fws[cur][3][tid] + b1v;
    }

    // ---- f. advance (static stride-GRID schedule) ----
    vt_cur = vt_nxt;
    if (have_nxt) {
      t_cur = t_nxt; j0_cur = j0_nxt; ct_cur = ct_nxt;
      vt_nxt += GRID;
      anext = 0;
      if (vt_nxt < total) {
        DECODE(vt_nxt, t_nxt, j0_nxt, ct_nxt);
        if (j0_nxt + row < ct_nxt) anext = perm[t_nxt * N_ATOMS + j0_nxt + row];
      }
    }
    cur ^= 1;
  }
#undef DECODE
#undef EPI_HALF
}

extern "C" void kernel_launch(void* const* d_in, const int* in_sizes, int n_in,
                              void* d_out, int out_size, void* d_ws, size_t ws_size,
                              hipStream_t stream) {
  const float* q  = (const float*)d_in[0];
  const int*   Z  = (const int*)d_in[1];
  const float* W0 = (const float*)d_in[2];
  const float* b0 = (const float*)d_in[3];
  const float* W1 = (const float*)d_in[4];
  const float* b1 = (const float*)d_in[5];
  float* out = (float*)d_out;

  char* ws = (char*)d_ws;
  int* hdr    = (int*)(ws);                        // cnt[4] + pad
  int* cnt    = hdr;
  int* perm   = (int*)(ws + 64);                   // 4*N ints = 2 MB
  unsigned short* W0s =
      (unsigned short*)(ws + 64 + (size_t)NTYPES * N_ATOMS * 4);  // 1 MB

  hipLaunchKernelGGL(init_kernel, dim3(1), dim3(64), 0, stream, hdr);
  hipLaunchKernelGGL(prep_kernel, dim3(512), dim3(256), 0, stream,
                     W0, Z, W0s, perm, cnt);
  hipLaunchKernelGGL(gemm_persist, dim3(GRID), dim3(256), 0, stream,
                     q, perm, cnt, W0s, b0, W1, b1, out);
}